// Round 1
// 390.297 us; speedup vs baseline: 1.0284x; 1.0284x over previous
//
#include <hip/hip_runtime.h>

// VertexUpdate: out[i] = (b_i, x_i, b_i - sum_{e:src[e]=i} c_e)
//
// R1: device atomicAdd scatter -> 771 us; WRITE 500 MB (16M x 32B sectors).
// R3: per-XCD replicas + wg-scope atomics -> identical (L2 thrash).
// R4: radix binning, cursor scatter -> 640 us (partition WRITE 455 MB).
// R5: LDS counting-sort + linear copy-out -> 429 us.
// R6: TPB 1024, register-staged int4/float4 loads, ulonglong2 aggregate
//     reads + LDS-staged float4 output -> 401 us.
//     rocprof: partition 130 us @ 24% HBM, VALUBusy 8.5%, occ 65% ->
//     latency-bound; 18 barriers/block from Hillis-Steele scan is the
//     prime suspect (~40K unexplained cycles/block).
// R7: (a) shuffle-based wave scan: 18 barriers -> 3; (b) eattr float4
//     loads issued BEFORE hist+scan so HBM latency hides under the scan;
//     (c) aggregate: 4-deep ulonglong2 MLP + early vattr loads.
//     Predict: partition ~100 us, aggregate ~95 us, total ~340 us.

#define BSHIFT 11
#define BSIZE (1 << BSHIFT)      // 2048 vertices per bucket
#define NBUCK_PAD 512            // padded bucket count (real: 489)
#define TILE 8192
#define TPB 1024

__global__ __launch_bounds__(TPB, 8)
void vu_partition(const int* __restrict__ src,
                  const float* __restrict__ eattr,
                  unsigned long long* __restrict__ pairs,
                  unsigned int* __restrict__ alloc,
                  int ne, int nbuck, int cap) {
    __shared__ unsigned long long sorted[TILE];   // 64 KB
    __shared__ unsigned int hist[NBUCK_PAD];
    __shared__ unsigned int base_l[NBUCK_PAD];
    __shared__ unsigned int cursor[NBUCK_PAD];
    __shared__ unsigned int gbase[NBUCK_PAD];
    __shared__ unsigned int wsum[8];              // per-wave scan sums
    __shared__ unsigned int wexcl[8];             // exclusive wave offsets

    int t = threadIdx.x;
    int tile0 = blockIdx.x * TILE;
    int lim = ne - tile0; if (lim > TILE) lim = TILE;
    bool full = (lim == TILE);

    if (t < NBUCK_PAD) hist[t] = 0u;
    __syncthreads();

    // 1) load src into registers (vector, once) + histogram.
    //    eattr loads issued NOW so their latency hides under hist+scan.
    int4 sA, sB;
    float4 cA0, cA1, cB0, cB1;
    if (full) {
        const int4* s4 = (const int4*)(src + tile0);
        sA = s4[t];          // edges tile0 + 4t .. +3
        sB = s4[t + TPB];    // edges tile0 + 4096 + 4t .. +3
        const float4* ef = (const float4*)eattr;   // 2 edges per float4
        int b0 = (tile0 >> 1) + 2 * t;
        cA0 = ef[b0];
        cA1 = ef[b0 + 1];
        cB0 = ef[b0 + 2048];
        cB1 = ef[b0 + 2049];
        atomicAdd(&hist[((unsigned)sA.x) >> BSHIFT], 1u);
        atomicAdd(&hist[((unsigned)sA.y) >> BSHIFT], 1u);
        atomicAdd(&hist[((unsigned)sA.z) >> BSHIFT], 1u);
        atomicAdd(&hist[((unsigned)sA.w) >> BSHIFT], 1u);
        atomicAdd(&hist[((unsigned)sB.x) >> BSHIFT], 1u);
        atomicAdd(&hist[((unsigned)sB.y) >> BSHIFT], 1u);
        atomicAdd(&hist[((unsigned)sB.z) >> BSHIFT], 1u);
        atomicAdd(&hist[((unsigned)sB.w) >> BSHIFT], 1u);
    } else {
        for (int i = t; i < lim; i += TPB)
            atomicAdd(&hist[((unsigned)src[tile0 + i]) >> BSHIFT], 1u);
    }
    __syncthreads();

    // 2) exclusive scan over 512 entries: shuffle wave-scan, 3 barriers
    //    (was: 9-step Hillis-Steele = 18 barriers).
    unsigned int mycnt = (t < NBUCK_PAD) ? hist[t] : 0u;
    unsigned int x = mycnt;
    #pragma unroll
    for (int off = 1; off < 64; off <<= 1) {
        unsigned int v = __shfl_up(x, off, 64);
        if ((t & 63) >= off) x += v;
    }
    if (t < NBUCK_PAD && (t & 63) == 63) wsum[t >> 6] = x;
    __syncthreads();
    if (t < 8) {
        unsigned int s = 0u;
        for (int k = 0; k < t; ++k) s += wsum[k];
        wexcl[t] = s;
    }
    __syncthreads();
    if (t < NBUCK_PAD) {
        unsigned int inc = x + wexcl[t >> 6];
        unsigned int excl = inc - mycnt;
        base_l[t] = excl;
        cursor[t] = excl;
        gbase[t] = (t < nbuck && mycnt) ? atomicAdd(&alloc[t], mycnt) : 0u;
    }
    __syncthreads();

    // 3) scatter into LDS sorted by bucket (src + eattr from registers)
#define VU_SCAT(sv, cv) do { \
        unsigned int q_ = ((unsigned)(sv)) >> BSHIFT; \
        unsigned int pos_ = atomicAdd(&cursor[q_], 1u); \
        sorted[pos_] = ((unsigned long long)__float_as_uint(cv) << 32) \
                       | (unsigned)(sv); } while (0)
    if (full) {
        VU_SCAT(sA.x, cA0.y); VU_SCAT(sA.y, cA0.w);
        VU_SCAT(sA.z, cA1.y); VU_SCAT(sA.w, cA1.w);
        VU_SCAT(sB.x, cB0.y); VU_SCAT(sB.y, cB0.w);
        VU_SCAT(sB.z, cB1.y); VU_SCAT(sB.w, cB1.w);
    } else {
        for (int i = t; i < lim; i += TPB) {
            int e = tile0 + i;
            int s = src[e];
            float2 ec = ((const float2*)eattr)[e];
            VU_SCAT(s, ec.y);
        }
    }
#undef VU_SCAT
    __syncthreads();

    // 4) linear copy-out: runs contiguous in LDS and global
    for (int i = t; i < lim; i += TPB) {
        unsigned long long p = sorted[i];
        unsigned int q = ((unsigned int)p) >> BSHIFT;
        unsigned int dst = q * (unsigned int)cap + gbase[q]
                         + ((unsigned int)i - base_l[q]);
        unsigned int hi = q * (unsigned int)cap + (unsigned int)cap - 1u;
        if (dst > hi) dst = hi;                    // OOB guard (never fires)
        pairs[dst] = p;
    }
}

__global__ __launch_bounds__(1024)
void vu_aggregate(const unsigned long long* __restrict__ pairs,
                  const unsigned int* __restrict__ alloc,
                  const float* __restrict__ vattr,
                  float* __restrict__ out,
                  int nv, int cap) {
    __shared__ float acc[BSIZE];                   // 8 KB
    __shared__ float obuf[BSIZE * 3];              // 24 KB
    int q = blockIdx.x;
    int t = threadIdx.x;
    acc[t] = 0.0f;
    acc[t + 1024] = 0.0f;

    // early vattr loads: latency hides under the pair loop
    int v0 = q << BSHIFT;
    int iv0 = v0 + t, iv1 = v0 + t + 1024;
    float2 va0 = make_float2(0.f, 0.f), va1 = make_float2(0.f, 0.f);
    if (iv0 < nv) va0 = ((const float2*)vattr)[iv0];
    if (iv1 < nv) va1 = ((const float2*)vattr)[iv1];
    __syncthreads();

    unsigned int cnt = alloc[q];
    if (cnt > (unsigned int)cap) cnt = (unsigned int)cap;
    const unsigned long long* p = pairs + (size_t)q * (size_t)cap;
    const ulonglong2* p2 = (const ulonglong2*)p;   // cap mult of 16 -> aligned
    unsigned int n2 = cnt >> 1;

#define VU_ACC(v64) do { \
        atomicAdd(&acc[((unsigned int)(v64)) & (BSIZE - 1)], \
                  __uint_as_float((unsigned int)((v64) >> 32))); } while (0)

    // 4-deep MLP: 4 independent 16B loads in flight per thread
    unsigned int i = t;
    for (; i + 3u * 1024u < n2; i += 4096u) {
        ulonglong2 v0 = p2[i];
        ulonglong2 v1 = p2[i + 1024u];
        ulonglong2 v2 = p2[i + 2048u];
        ulonglong2 v3 = p2[i + 3072u];
        VU_ACC(v0.x); VU_ACC(v0.y);
        VU_ACC(v1.x); VU_ACC(v1.y);
        VU_ACC(v2.x); VU_ACC(v2.y);
        VU_ACC(v3.x); VU_ACC(v3.y);
    }
    for (; i < n2; i += 1024u) {
        ulonglong2 v = p2[i];
        VU_ACC(v.x); VU_ACC(v.y);
    }
    if (t == 0 && (cnt & 1u)) {
        unsigned long long v = p[cnt - 1];
        VU_ACC(v);
    }
#undef VU_ACC
    __syncthreads();

    if (iv0 < nv) {
        obuf[3 * t + 0] = va0.x;
        obuf[3 * t + 1] = va0.y;
        obuf[3 * t + 2] = va0.x - acc[t];
    }
    {
        int i2 = t + 1024;
        if (iv1 < nv) {
            obuf[3 * i2 + 0] = va1.x;
            obuf[3 * i2 + 1] = va1.y;
            obuf[3 * i2 + 2] = va1.x - acc[i2];
        }
    }
    __syncthreads();

    // coalesced float4 write of the bucket's contiguous out-slice
    long fbase = (long)q * (BSIZE * 3);
    int nfl = 3 * nv - (int)fbase;
    if (nfl > BSIZE * 3) nfl = BSIZE * 3;
    if (nfl > 0) {
        float4* o4 = (float4*)(out + fbase);       // fbase mult of 4
        const float4* s4 = (const float4*)obuf;
        int n4 = nfl >> 2;
        for (int j = t; j < n4; j += 1024) o4[j] = s4[j];
        for (int j = (n4 << 2) + t; j < nfl; j += 1024) out[fbase + j] = obuf[j];
    }
}

// ---- fallback (round-1 path, 961 us) if ws is too small ----
__global__ void vu_init_kernel(const float* __restrict__ vattr,
                               float* __restrict__ out, int n) {
    int i = blockIdx.x * blockDim.x + threadIdx.x;
    if (i < n) {
        float2 v = ((const float2*)vattr)[i];
        out[3 * i + 0] = v.x;
        out[3 * i + 1] = v.y;
        out[3 * i + 2] = v.x;
    }
}

__global__ void vu_scatter_kernel(const int* __restrict__ src,
                                  const float* __restrict__ eattr,
                                  float* __restrict__ out, int ne) {
    int t = blockIdx.x * blockDim.x + threadIdx.x;
    int e0 = t * 4;
    if (e0 + 3 < ne) {
        int4 idx = ((const int4*)src)[t];
        float4 a = ((const float4*)eattr)[2 * t + 0];
        float4 b = ((const float4*)eattr)[2 * t + 1];
        atomicAdd(&out[3 * idx.x + 2], -a.y);
        atomicAdd(&out[3 * idx.y + 2], -a.w);
        atomicAdd(&out[3 * idx.z + 2], -b.y);
        atomicAdd(&out[3 * idx.w + 2], -b.w);
    } else {
        for (int e = e0; e < ne; ++e)
            atomicAdd(&out[3 * src[e] + 2], -eattr[2 * e + 1]);
    }
}

extern "C" void kernel_launch(void* const* d_in, const int* in_sizes, int n_in,
                              void* d_out, int out_size, void* d_ws, size_t ws_size,
                              hipStream_t stream) {
    const float* vattr = (const float*)d_in[0];
    const int* edges = (const int*)d_in[1];   // (2, N_E); row 0 = src
    const float* eattr = (const float*)d_in[2];
    float* out = (float*)d_out;

    int nv = in_sizes[0] / 2;   // 1,000,000
    int ne = in_sizes[2] / 2;   // 16,000,000

    int nbuck = (nv + BSIZE - 1) >> BSHIFT;          // 489
    int mean = ne / nbuck;                           // ~32.7K
    int cap = mean + mean / 8 + 1024;                // +~13% slack
    cap = (cap + 15) & ~15;

    size_t alloc_bytes = 4096;
    size_t pair_bytes = (size_t)nbuck * (size_t)cap * 8ull;
    size_t need = alloc_bytes + pair_bytes;          // ~145 MB

    if (ws_size >= need && nbuck <= NBUCK_PAD) {
        unsigned int* alloc = (unsigned int*)d_ws;
        unsigned long long* pairs = (unsigned long long*)((char*)d_ws + alloc_bytes);
        (void)hipMemsetAsync(alloc, 0, (size_t)nbuck * 4, stream);

        int p1_blocks = (ne + TILE - 1) / TILE;      // 1954
        vu_partition<<<p1_blocks, TPB, 0, stream>>>(edges, eattr, pairs, alloc,
                                                    ne, nbuck, cap);
        vu_aggregate<<<nbuck, 1024, 0, stream>>>(pairs, alloc, vattr, out, nv, cap);
    } else {
        int threads = 256;
        int blocks = (nv + threads - 1) / threads;
        vu_init_kernel<<<blocks, threads, 0, stream>>>(vattr, out, nv);
        int nt = (ne + 3) / 4;
        blocks = (nt + threads - 1) / threads;
        vu_scatter_kernel<<<blocks, threads, 0, stream>>>(edges, eattr, out, ne);
    }
}